// Round 6
// baseline (4306.011 us; speedup 1.0000x reference)
//
#include <hip/hip_runtime.h>
#include <stdint.h>

// BidirectionalRNNClassifier on MI355X.
//   embed = inp @ U / 16 + b              (MFMA bf16 hi/lo, ~fp32 accurate)
//   512 sequential steps x 2 directions:  carry = erf(e_t + carry) @ W / 32
//   out = [s_fwd_last, s_bwd_last] @ v / 32
// Recurrence v5 = round-3 (proven) + memory-schedule fix:
//   4 groups (dir x batch-half of 32 rows) x 16 wgs; wg owns 64-col W slice
//   (bf16, frag-linear) in 128 KB LDS; exchange via MALL with sc0 sc1.
//   FIX (H3): e-prefetch moved AFTER the flag poll, issued behind the 32
//   s-loads, so the poll's vmcnt(0) no longer drains HBM e-loads. All
//   in-loop VMEM is inline asm; chunked waits vmcnt(40/32/24/16) feed the
//   4 MFMA chunks; final vmcnt(0)+sched_barrier covers e-loads (raw bits,
//   converted only next iteration - rule #18 safe).

#define TS 512
#define NB 64
#define DI 256
#define DD 1024
#define GW 16

typedef float f32x4 __attribute__((ext_vector_type(4)));
typedef short bf16x8 __attribute__((ext_vector_type(8)));

__device__ __forceinline__ unsigned short f32_bf16(float x){
  unsigned u = __float_as_uint(x);
  u += 0x7FFFu + ((u >> 16) & 1u);          // round-nearest-even
  return (unsigned short)(u >> 16);
}
__device__ __forceinline__ float bf16_f32(unsigned short h){
  return __uint_as_float(((unsigned)h) << 16);
}

// ---- W prep: W[k][n] -> bf16, frag-linear per 64-col slice ----
// slice j (64 cols), sub-tile nt (16 cols), kstep ks, lane, elem e:
//   k = ks*32 + 8*(lane>>4) + e, n = j*64 + nt*16 + (lane&15)
__global__ __launch_bounds__(256) void wprep(const float* __restrict__ W,
                                             unsigned short* __restrict__ whi){
  int idx = blockIdx.x * 256 + threadIdx.x;   // = k*1024 + n
  int k = idx >> 10, n = idx & 1023;
  unsigned short h = f32_bf16(W[idx]);
  int j  = n >> 6;
  int nt = (n >> 4) & 3;
  int ks = k >> 5;
  int e  = k & 7;
  int lane = (((k >> 3) & 3) << 4) | (n & 15);
  whi[(size_t)j * 65536 + nt * 16384 + ks * 512 + lane * 8 + e] = h;
}

// ---- embed GEMM: e[t][b][d] = sum_i inp[b][t][i]*U[i][d]/16 + bias[d] ----
template<int EF32>
__global__ __launch_bounds__(256, 2) void embed_k(const float* __restrict__ inp,
                                                  const float* __restrict__ U,
                                                  const float* __restrict__ bias,
                                                  void* __restrict__ e_out){
  __shared__ __attribute__((aligned(16))) unsigned short Ah[8192], Al[8192], Bh[8192], Bl[8192];
  const int tid = threadIdx.x;
  const int w = tid >> 6, l = tid & 63;
  const int bx = blockIdx.x;
  const int tc = bx & 15, tr = bx >> 4;
  const int R0 = tr * 64, C0 = tc * 64;

  f32x4 acc[4];
  #pragma unroll
  for (int nt = 0; nt < 4; ++nt) acc[nt] = (f32x4){0.f, 0.f, 0.f, 0.f};

  for (int kc = 0; kc < 2; ++kc){
    if (kc) __syncthreads();
    unsigned int* AhU = (unsigned int*)Ah;
    unsigned int* AlU = (unsigned int*)Al;
    for (int it = 0; it < 8; ++it){
      int fi = it * 256 + tid;
      int r = fi >> 5, k4 = fi & 31;
      float4 a = *(const float4*)&inp[((size_t)(R0 + r)) * DI + kc * 128 + k4 * 4];
      unsigned short hx = f32_bf16(a.x), hy = f32_bf16(a.y), hz = f32_bf16(a.z), hw = f32_bf16(a.w);
      unsigned short lx = f32_bf16(a.x - bf16_f32(hx)), ly = f32_bf16(a.y - bf16_f32(hy));
      unsigned short lz = f32_bf16(a.z - bf16_f32(hz)), lw = f32_bf16(a.w - bf16_f32(hw));
      int o = (r * 64 + k4 * 2) ^ ((r & 7) << 2);
      AhU[o]     = (unsigned)hx | ((unsigned)hy << 16);
      AhU[o + 1] = (unsigned)hz | ((unsigned)hw << 16);
      AlU[o]     = (unsigned)lx | ((unsigned)ly << 16);
      AlU[o + 1] = (unsigned)lz | ((unsigned)lw << 16);
    }
    for (int it = 0; it < 8; ++it){
      int fi = it * 256 + tid;
      int kk = fi >> 4, c4 = fi & 15;
      float4 u4 = *(const float4*)&U[((size_t)(kc * 128 + kk)) * DD + C0 + c4 * 4];
      float vals[4] = {u4.x, u4.y, u4.z, u4.w};
      #pragma unroll
      for (int q = 0; q < 4; ++q){
        int c = c4 * 4 + q;
        unsigned short h  = f32_bf16(vals[q]);
        unsigned short lo = f32_bf16(vals[q] - bf16_f32(h));
        int o = (c * 128 + kk) ^ ((c & 7) << 3);
        Bh[o] = h; Bl[o] = lo;
      }
    }
    __syncthreads();
    const int arow = (w << 4) | (l & 15);
    const int koff = (l >> 4) << 3;
    #pragma unroll
    for (int ks = 0; ks < 4; ++ks){
      int ao = (arow * 128 + ks * 32 + koff) ^ ((arow & 7) << 3);
      bf16x8 ah = *(const bf16x8*)&Ah[ao];
      bf16x8 al = *(const bf16x8*)&Al[ao];
      #pragma unroll
      for (int nt = 0; nt < 4; ++nt){
        int brow = (nt << 4) | (l & 15);
        int bo = (brow * 128 + ks * 32 + koff) ^ ((brow & 7) << 3);
        bf16x8 bh = *(const bf16x8*)&Bh[bo];
        bf16x8 bl = *(const bf16x8*)&Bl[bo];
        acc[nt] = __builtin_amdgcn_mfma_f32_16x16x32_bf16(ah, bh, acc[nt], 0, 0, 0);
        acc[nt] = __builtin_amdgcn_mfma_f32_16x16x32_bf16(ah, bl, acc[nt], 0, 0, 0);
        acc[nt] = __builtin_amdgcn_mfma_f32_16x16x32_bf16(al, bh, acc[nt], 0, 0, 0);
      }
    }
  }
  #pragma unroll
  for (int nt = 0; nt < 4; ++nt){
    int d = C0 + (nt << 4) + (l & 15);
    float bv = bias[d];
    #pragma unroll
    for (int i = 0; i < 4; ++i){
      int R = R0 + (w << 4) + ((l >> 4) << 2) + i;
      int b = R >> 9, t = R & 511;
      float val = acc[nt][i] * 0.0625f + bv;
      size_t eo = (((size_t)(t * NB + b)) << 10) | (unsigned)d;
      if (EF32) ((float*)e_out)[eo] = val;
      else      ((unsigned short*)e_out)[eo] = f32_bf16(val);
    }
  }
}

// ---- recurrence: 64 wgs x 128 threads; 4 groups x 16 wgs ----
template<int EF32>
__global__ __launch_bounds__(128, 1) void recur(const void* __restrict__ e_in,
                                                const unsigned short* __restrict__ whi,
                                                unsigned short* __restrict__ sbuf,
                                                float* __restrict__ sfin,
                                                unsigned int* __restrict__ flags){
  __shared__ __attribute__((aligned(16))) unsigned short Wh[65536];   // 128 KB
  const int tid = threadIdx.x;
  const int w = tid >> 6, l = tid & 63;
  const int bid = blockIdx.x;
  const int g = bid >> 4;           // group = dir*2 + batch-chunk
  const int j = bid & 15;           // 64-col N-slice
  const int dir = g >> 1, rb0 = (g & 1) * 32;

  { // stage this wg's W slice into LDS (frag-linear)
    const uint4* src = (const uint4*)(whi + (size_t)j * 65536);
    uint4* dst = (uint4*)Wh;
    for (int i = tid; i < 8192; i += 128) dst[i] = src[i];
  }
  __syncthreads();

  unsigned int* gflags = flags + g * GW;
  unsigned short* sbg = sbuf + (size_t)g * 2 * 32 * DD;

  // thread geometry (C-layout of 16x16 MFMA): lane l -> col l&15, rows (l>>4)*4+i
  const int d0 = j * 64;
  const int colq = l & 15;
  const int rl = (w << 4) + ((l >> 4) << 2);   // this thread's 4-row base
  const float inv32 = 0.03125f;

  f32x4 acc[4];
  #pragma unroll
  for (int nt = 0; nt < 4; ++nt) acc[nt] = (f32x4){0.f, 0.f, 0.f, 0.f};

  // e held as RAW bits; converted only after the loop-end vmcnt(0) boundary.
  unsigned evraw[4][4];
  {
    int te0 = dir ? (TS - 1) : 0;
    #pragma unroll
    for (int nt = 0; nt < 4; ++nt)
      #pragma unroll
      for (int i = 0; i < 4; ++i){
        size_t o = (((size_t)(te0 * NB + rb0 + rl + i)) << 10)
                 | (unsigned)(d0 + nt * 16 + colq);
        evraw[nt][i] = EF32 ? __float_as_uint(((const float*)e_in)[o])
                            : (unsigned)((const unsigned short*)e_in)[o];
      }
  }

  const bf16x8* wp = (const bf16x8*)Wh;
  #pragma unroll 1
  for (int t = 0; t < TS; ++t){
    float sv[4][4];
    #pragma unroll
    for (int nt = 0; nt < 4; ++nt)
      #pragma unroll
      for (int i = 0; i < 4; ++i){
        float e = EF32 ? __uint_as_float(evraw[nt][i])
                       : __uint_as_float(evraw[nt][i] << 16);
        sv[nt][i] = erff(e + acc[nt][i] * inv32);
      }

    if (t == TS - 1){
      #pragma unroll
      for (int nt = 0; nt < 4; ++nt)
        #pragma unroll
        for (int i = 0; i < 4; ++i)
          sfin[(((size_t)(dir * NB + rb0 + rl + i)) << 10)
               | (unsigned)(d0 + nt * 16 + colq)] = sv[nt][i];
      break;
    }

    unsigned short* sb = sbg + (t & 1) * 32768;   // double buffer, 32x1024
    #pragma unroll
    for (int nt = 0; nt < 4; ++nt)
      #pragma unroll
      for (int i = 0; i < 4; ++i){
        unsigned short* p = sb + (((unsigned)(rl + i)) << 10)
                               + (unsigned)(d0 + nt * 16 + colq);
        unsigned val = f32_bf16(sv[nt][i]);
        asm volatile("global_store_short %0, %1, off sc0 sc1" :: "v"(p), "v"(val) : "memory");
      }

    asm volatile("s_waitcnt vmcnt(0)" ::: "memory");  // drain asm stores explicitly
    __syncthreads();                                   // join both waves
    if (tid == 0)
      __hip_atomic_store(&gflags[j], (unsigned)(t + 1),
                         __ATOMIC_RELAXED, __HIP_MEMORY_SCOPE_AGENT);

    { // poll 16 flags (proven round-3 form); nothing else outstanding now
      const unsigned tgt = (unsigned)(t + 1);
      unsigned f; int spins = 0;
      do {
        f = __hip_atomic_load(&gflags[l & 15], __ATOMIC_RELAXED, __HIP_MEMORY_SCOPE_AGENT);
        if (++spins > (1 << 18)) break;               // fail loud, never hang
      } while (!__all((int)(f >= tgt)));
    }
    asm volatile("" ::: "memory");

    // Issue ALL in-loop VMEM as asm, in order: 32 s-loads (sc0 sc1), then
    // 16 e-loads (plain cached). vmcnt waits: oldest-first semantics.
    bf16x8 af[4][8];
    const unsigned short* srow = sb + (((unsigned)((w << 4) + (l & 15))) << 10) + ((l >> 4) << 3);
    #pragma unroll
    for (int c = 0; c < 4; ++c)
      #pragma unroll
      for (int ki = 0; ki < 8; ++ki){
        const unsigned short* p = srow + (c * 8 + ki) * 32;
        asm volatile("global_load_dwordx4 %0, %1, off sc0 sc1" : "=v"(af[c][ki]) : "v"(p));
      }
    {
      int te2 = dir ? (TS - 2 - t) : (t + 1);
      #pragma unroll
      for (int nt = 0; nt < 4; ++nt)
        #pragma unroll
        for (int i = 0; i < 4; ++i){
          if (EF32){
            const float* p = (const float*)e_in
              + ((((size_t)(te2 * NB + rb0 + rl + i)) << 10)
                 | (unsigned)(d0 + nt * 16 + colq));
            asm volatile("global_load_dword %0, %1, off" : "=v"(evraw[nt][i]) : "v"(p));
          } else {
            const unsigned short* p = (const unsigned short*)e_in
              + ((((size_t)(te2 * NB + rb0 + rl + i)) << 10)
                 | (unsigned)(d0 + nt * 16 + colq));
            asm volatile("global_load_ushort %0, %1, off" : "=v"(evraw[nt][i]) : "v"(p));
          }
        }
    }

    // 4 MFMA chunks over ks; exact in-order vmcnt (48 outstanding at start):
    // af[0] done at vmcnt(40), af[1] at 32, af[2] at 24, af[3] at 16.
    f32x4 c0 = (f32x4){0,0,0,0}, c1 = (f32x4){0,0,0,0};
    f32x4 c2 = (f32x4){0,0,0,0}, c3 = (f32x4){0,0,0,0};
    asm volatile("s_waitcnt vmcnt(40)" ::: "memory");
    __builtin_amdgcn_sched_barrier(0);
    #pragma unroll
    for (int ki = 0; ki < 8; ++ki){
      int ks = ki;
      c0 = __builtin_amdgcn_mfma_f32_16x16x32_bf16(af[0][ki], wp[          ks * 64 + l], c0, 0, 0, 0);
      c1 = __builtin_amdgcn_mfma_f32_16x16x32_bf16(af[0][ki], wp[2048 +    ks * 64 + l], c1, 0, 0, 0);
      c2 = __builtin_amdgcn_mfma_f32_16x16x32_bf16(af[0][ki], wp[4096 +    ks * 64 + l], c2, 0, 0, 0);
      c3 = __builtin_amdgcn_mfma_f32_16x16x32_bf16(af[0][ki], wp[6144 +    ks * 64 + l], c3, 0, 0, 0);
    }
    asm volatile("s_waitcnt vmcnt(32)" ::: "memory");
    __builtin_amdgcn_sched_barrier(0);
    #pragma unroll
    for (int ki = 0; ki < 8; ++ki){
      int ks = 8 + ki;
      c0 = __builtin_amdgcn_mfma_f32_16x16x32_bf16(af[1][ki], wp[          ks * 64 + l], c0, 0, 0, 0);
      c1 = __builtin_amdgcn_mfma_f32_16x16x32_bf16(af[1][ki], wp[2048 +    ks * 64 + l], c1, 0, 0, 0);
      c2 = __builtin_amdgcn_mfma_f32_16x16x32_bf16(af[1][ki], wp[4096 +    ks * 64 + l], c2, 0, 0, 0);
      c3 = __builtin_amdgcn_mfma_f32_16x16x32_bf16(af[1][ki], wp[6144 +    ks * 64 + l], c3, 0, 0, 0);
    }
    asm volatile("s_waitcnt vmcnt(24)" ::: "memory");
    __builtin_amdgcn_sched_barrier(0);
    #pragma unroll
    for (int ki = 0; ki < 8; ++ki){
      int ks = 16 + ki;
      c0 = __builtin_amdgcn_mfma_f32_16x16x32_bf16(af[2][ki], wp[          ks * 64 + l], c0, 0, 0, 0);
      c1 = __builtin_amdgcn_mfma_f32_16x16x32_bf16(af[2][ki], wp[2048 +    ks * 64 + l], c1, 0, 0, 0);
      c2 = __builtin_amdgcn_mfma_f32_16x16x32_bf16(af[2][ki], wp[4096 +    ks * 64 + l], c2, 0, 0, 0);
      c3 = __builtin_amdgcn_mfma_f32_16x16x32_bf16(af[2][ki], wp[6144 +    ks * 64 + l], c3, 0, 0, 0);
    }
    asm volatile("s_waitcnt vmcnt(16)" ::: "memory");
    __builtin_amdgcn_sched_barrier(0);
    #pragma unroll
    for (int ki = 0; ki < 8; ++ki){
      int ks = 24 + ki;
      c0 = __builtin_amdgcn_mfma_f32_16x16x32_bf16(af[3][ki], wp[          ks * 64 + l], c0, 0, 0, 0);
      c1 = __builtin_amdgcn_mfma_f32_16x16x32_bf16(af[3][ki], wp[2048 +    ks * 64 + l], c1, 0, 0, 0);
      c2 = __builtin_amdgcn_mfma_f32_16x16x32_bf16(af[3][ki], wp[4096 +    ks * 64 + l], c2, 0, 0, 0);
      c3 = __builtin_amdgcn_mfma_f32_16x16x32_bf16(af[3][ki], wp[6144 +    ks * 64 + l], c3, 0, 0, 0);
    }
    asm volatile("s_waitcnt vmcnt(0)" ::: "memory");   // e-loads for next erf
    __builtin_amdgcn_sched_barrier(0);
    acc[0] = c0; acc[1] = c1; acc[2] = c2; acc[3] = c3;
  }
}

// ---- final: out[b] = ([sf, sb] @ v) / 32 ----
__global__ __launch_bounds__(256) void finale(const float* __restrict__ sfin,
                                              const float* __restrict__ v,
                                              float* __restrict__ out){
  const int b = blockIdx.x, tid = threadIdx.x;
  float p = 0.f;
  for (int dd = tid; dd < 2 * DD; dd += 256){
    int dir = dd >> 10, d = dd & 1023;
    p += sfin[(((size_t)(dir * NB + b)) << 10) | (unsigned)d] * v[dd];
  }
  #pragma unroll
  for (int off = 32; off > 0; off >>= 1) p += __shfl_down(p, off, 64);
  __shared__ float red[4];
  if ((tid & 63) == 0) red[tid >> 6] = p;
  __syncthreads();
  if (tid == 0) out[b] = (red[0] + red[1] + red[2] + red[3]) * 0.03125f;
}

extern "C" void kernel_launch(void* const* d_in, const int* in_sizes, int n_in,
                              void* d_out, int out_size, void* d_ws, size_t ws_size,
                              hipStream_t stream){
  const float* inp  = (const float*)d_in[0];
  const float* W    = (const float*)d_in[1];
  const float* U    = (const float*)d_in[2];
  const float* bias = (const float*)d_in[3];
  const float* v    = (const float*)d_in[4];
  float* out = (float*)d_out;

  const size_t e_f32_bytes = (size_t)TS * NB * DD * 4;               // 134 MB
  const size_t rest = 2u * 1024 * 1024 + 512u * 1024 + 512u * 1024 + 4096;
  const int ef32 = (ws_size >= e_f32_bytes + rest) ? 1 : 0;

  char* p = (char*)d_ws;
  void* e_buf = (void*)p;              p += ef32 ? e_f32_bytes : e_f32_bytes / 2;
  unsigned short* whi  = (unsigned short*)p; p += 2u * 1024 * 1024;
  unsigned short* sbuf = (unsigned short*)p; p += 512u * 1024;
  float* sfin = (float*)p;             p += 512u * 1024;
  unsigned int* flags = (unsigned int*)p;

  hipMemsetAsync(flags, 0, 4096, stream);
  hipLaunchKernelGGL(wprep, dim3(4096), dim3(256), 0, stream, W, whi);
  if (ef32) hipLaunchKernelGGL((embed_k<1>), dim3(8192), dim3(256), 0, stream, inp, U, bias, e_buf);
  else      hipLaunchKernelGGL((embed_k<0>), dim3(8192), dim3(256), 0, stream, inp, U, bias, e_buf);
  if (ef32) hipLaunchKernelGGL((recur<1>), dim3(64), dim3(128), 0, stream,
                               (const void*)e_buf, whi, sbuf, sfin, flags);
  else      hipLaunchKernelGGL((recur<0>), dim3(64), dim3(128), 0, stream,
                               (const void*)e_buf, whi, sbuf, sfin, flags);
  hipLaunchKernelGGL(finale, dim3(64), dim3(256), 0, stream, sfin, v, out);
}

// Round 7
// 3852.610 us; speedup vs baseline: 1.1177x; 1.1177x over previous
//
#include <hip/hip_runtime.h>
#include <stdint.h>

// BidirectionalRNNClassifier on MI355X.
//   embed = inp @ U / 16 + b              (MFMA bf16 hi/lo, ~fp32 accurate)
//   512 sequential steps x 2 directions:  carry = erf(e_t + carry) @ W / 32
//   out = [s_fwd_last, s_bwd_last] @ v / 32
// Recurrence v7 = round-3 proven schedule + per-WAVE flags, NO per-step
// barrier. Wave w of wg j produces rows 16w..16w+15 x cols 64j..64j+63;
// those bytes are consumed only by same-index waves of peer wgs, so wave-0s
// and wave-1s are two independent sync cliques. Publish is racy (r3
// semantics, measured safe: consumer pays flag-RT + load-RT after our
// store issue; stores land ~1 RT earlier). Exchange via MALL (sc0 sc1).
// e-prefetch BEFORE the poll (r6 showed moving it after costs ~1 us/step);
// s-loads 8/8 double-buffered interleaved with MFMA chunks (r3 verbatim).

#define TS 512
#define NB 64
#define DI 256
#define DD 1024
#define GW 16
#define FSTRIDE 64     // u32 per group's flag block

typedef float f32x4 __attribute__((ext_vector_type(4)));
typedef short bf16x8 __attribute__((ext_vector_type(8)));

__device__ __forceinline__ unsigned short f32_bf16(float x){
  unsigned u = __float_as_uint(x);
  u += 0x7FFFu + ((u >> 16) & 1u);          // round-nearest-even
  return (unsigned short)(u >> 16);
}
__device__ __forceinline__ float bf16_f32(unsigned short h){
  return __uint_as_float(((unsigned)h) << 16);
}

// ---- W prep: W[k][n] -> bf16, frag-linear per 64-col slice ----
__global__ __launch_bounds__(256) void wprep(const float* __restrict__ W,
                                             unsigned short* __restrict__ whi){
  int idx = blockIdx.x * 256 + threadIdx.x;   // = k*1024 + n
  int k = idx >> 10, n = idx & 1023;
  unsigned short h = f32_bf16(W[idx]);
  int j  = n >> 6;
  int nt = (n >> 4) & 3;
  int ks = k >> 5;
  int e  = k & 7;
  int lane = (((k >> 3) & 3) << 4) | (n & 15);
  whi[(size_t)j * 65536 + nt * 16384 + ks * 512 + lane * 8 + e] = h;
}

// ---- embed GEMM: e[t][b][d] = sum_i inp[b][t][i]*U[i][d]/16 + bias[d] ----
template<int EF32>
__global__ __launch_bounds__(256, 2) void embed_k(const float* __restrict__ inp,
                                                  const float* __restrict__ U,
                                                  const float* __restrict__ bias,
                                                  void* __restrict__ e_out){
  __shared__ __attribute__((aligned(16))) unsigned short Ah[8192], Al[8192], Bh[8192], Bl[8192];
  const int tid = threadIdx.x;
  const int w = tid >> 6, l = tid & 63;
  const int bx = blockIdx.x;
  const int tc = bx & 15, tr = bx >> 4;
  const int R0 = tr * 64, C0 = tc * 64;

  f32x4 acc[4];
  #pragma unroll
  for (int nt = 0; nt < 4; ++nt) acc[nt] = (f32x4){0.f, 0.f, 0.f, 0.f};

  for (int kc = 0; kc < 2; ++kc){
    if (kc) __syncthreads();
    unsigned int* AhU = (unsigned int*)Ah;
    unsigned int* AlU = (unsigned int*)Al;
    for (int it = 0; it < 8; ++it){
      int fi = it * 256 + tid;
      int r = fi >> 5, k4 = fi & 31;
      float4 a = *(const float4*)&inp[((size_t)(R0 + r)) * DI + kc * 128 + k4 * 4];
      unsigned short hx = f32_bf16(a.x), hy = f32_bf16(a.y), hz = f32_bf16(a.z), hw = f32_bf16(a.w);
      unsigned short lx = f32_bf16(a.x - bf16_f32(hx)), ly = f32_bf16(a.y - bf16_f32(hy));
      unsigned short lz = f32_bf16(a.z - bf16_f32(hz)), lw = f32_bf16(a.w - bf16_f32(hw));
      int o = (r * 64 + k4 * 2) ^ ((r & 7) << 2);
      AhU[o]     = (unsigned)hx | ((unsigned)hy << 16);
      AhU[o + 1] = (unsigned)hz | ((unsigned)hw << 16);
      AlU[o]     = (unsigned)lx | ((unsigned)ly << 16);
      AlU[o + 1] = (unsigned)lz | ((unsigned)lw << 16);
    }
    for (int it = 0; it < 8; ++it){
      int fi = it * 256 + tid;
      int kk = fi >> 4, c4 = fi & 15;
      float4 u4 = *(const float4*)&U[((size_t)(kc * 128 + kk)) * DD + C0 + c4 * 4];
      float vals[4] = {u4.x, u4.y, u4.z, u4.w};
      #pragma unroll
      for (int q = 0; q < 4; ++q){
        int c = c4 * 4 + q;
        unsigned short h  = f32_bf16(vals[q]);
        unsigned short lo = f32_bf16(vals[q] - bf16_f32(h));
        int o = (c * 128 + kk) ^ ((c & 7) << 3);
        Bh[o] = h; Bl[o] = lo;
      }
    }
    __syncthreads();
    const int arow = (w << 4) | (l & 15);
    const int koff = (l >> 4) << 3;
    #pragma unroll
    for (int ks = 0; ks < 4; ++ks){
      int ao = (arow * 128 + ks * 32 + koff) ^ ((arow & 7) << 3);
      bf16x8 ah = *(const bf16x8*)&Ah[ao];
      bf16x8 al = *(const bf16x8*)&Al[ao];
      #pragma unroll
      for (int nt = 0; nt < 4; ++nt){
        int brow = (nt << 4) | (l & 15);
        int bo = (brow * 128 + ks * 32 + koff) ^ ((brow & 7) << 3);
        bf16x8 bh = *(const bf16x8*)&Bh[bo];
        bf16x8 bl = *(const bf16x8*)&Bl[bo];
        acc[nt] = __builtin_amdgcn_mfma_f32_16x16x32_bf16(ah, bh, acc[nt], 0, 0, 0);
        acc[nt] = __builtin_amdgcn_mfma_f32_16x16x32_bf16(ah, bl, acc[nt], 0, 0, 0);
        acc[nt] = __builtin_amdgcn_mfma_f32_16x16x32_bf16(al, bh, acc[nt], 0, 0, 0);
      }
    }
  }
  #pragma unroll
  for (int nt = 0; nt < 4; ++nt){
    int d = C0 + (nt << 4) + (l & 15);
    float bv = bias[d];
    #pragma unroll
    for (int i = 0; i < 4; ++i){
      int R = R0 + (w << 4) + ((l >> 4) << 2) + i;
      int b = R >> 9, t = R & 511;
      float val = acc[nt][i] * 0.0625f + bv;
      size_t eo = (((size_t)(t * NB + b)) << 10) | (unsigned)d;
      if (EF32) ((float*)e_out)[eo] = val;
      else      ((unsigned short*)e_out)[eo] = f32_bf16(val);
    }
  }
}

template<int EF32>
__device__ __forceinline__ float load_e(const void* e, int te, int b, int d){
  size_t o = (((size_t)(te * NB + b)) << 10) | (unsigned)d;
  if (EF32) return ((const float*)e)[o];
  return bf16_f32(((const unsigned short*)e)[o]);
}

// ---- recurrence: 64 wgs x 128 threads; 4 groups x 16 wgs; per-WAVE flags ----
template<int EF32>
__global__ __launch_bounds__(128, 1) void recur(const void* __restrict__ e_in,
                                                const unsigned short* __restrict__ whi,
                                                unsigned short* __restrict__ sbuf,
                                                float* __restrict__ sfin,
                                                unsigned int* __restrict__ flags){
  __shared__ __attribute__((aligned(16))) unsigned short Wh[65536];   // 128 KB
  const int tid = threadIdx.x;
  const int w = tid >> 6, l = tid & 63;
  const int bid = blockIdx.x;
  const int g = bid >> 4;           // group = dir*2 + batch-chunk
  const int j = bid & 15;           // 64-col N-slice
  const int dir = g >> 1, rb0 = (g & 1) * 32;

  { // stage this wg's W slice into LDS (frag-linear, once)
    const uint4* src = (const uint4*)(whi + (size_t)j * 65536);
    uint4* dst = (uint4*)Wh;
    for (int i = tid; i < 8192; i += 128) dst[i] = src[i];
  }
  __syncthreads();                  // only barrier in this kernel

  unsigned int* gflags = flags + g * FSTRIDE;   // [16 wgs][2 waves]
  unsigned short* sbg = sbuf + (size_t)g * 2 * 32 * DD;

  const int d0 = j * 64;
  const int colq = l & 15;
  const int rl = (w << 4) + ((l >> 4) << 2);   // this thread's 4-row base
  const float inv32 = 0.03125f;

  f32x4 acc[4];
  #pragma unroll
  for (int nt = 0; nt < 4; ++nt) acc[nt] = (f32x4){0.f, 0.f, 0.f, 0.f};

  float ev[4][4];
  {
    int te0 = dir ? (TS - 1) : 0;
    #pragma unroll
    for (int nt = 0; nt < 4; ++nt)
      #pragma unroll
      for (int i = 0; i < 4; ++i)
        ev[nt][i] = load_e<EF32>(e_in, te0, rb0 + rl + i, d0 + nt * 16 + colq);
  }

  const bf16x8* wp = (const bf16x8*)Wh;
  for (int t = 0; t < TS; ++t){
    float sv[4][4];
    #pragma unroll
    for (int nt = 0; nt < 4; ++nt)
      #pragma unroll
      for (int i = 0; i < 4; ++i)
        sv[nt][i] = erff(ev[nt][i] + acc[nt][i] * inv32);

    if (t == TS - 1){
      #pragma unroll
      for (int nt = 0; nt < 4; ++nt)
        #pragma unroll
        for (int i = 0; i < 4; ++i)
          sfin[(((size_t)(dir * NB + rb0 + rl + i)) << 10)
               | (unsigned)(d0 + nt * 16 + colq)] = sv[nt][i];
      break;
    }

    unsigned short* sb = sbg + (t & 1) * 32768;   // double buffer, 32x1024
    #pragma unroll
    for (int nt = 0; nt < 4; ++nt)
      #pragma unroll
      for (int i = 0; i < 4; ++i){
        unsigned short* p = sb + (((unsigned)(rl + i)) << 10)
                               + (unsigned)(d0 + nt * 16 + colq);
        unsigned val = f32_bf16(sv[nt][i]);
        asm volatile("global_store_short %0, %1, off sc0 sc1" :: "v"(p), "v"(val) : "memory");
      }

    // per-WAVE racy publish: flag store follows this wave's data stores in
    // issue order; no barrier. Consumer pays flag-RT + load-RT after this,
    // stores land ~1 RT earlier (r3-proven margin).
    if (l == 0)
      __hip_atomic_store(&gflags[j * 2 + w], (unsigned)(t + 1),
                         __ATOMIC_RELAXED, __HIP_MEMORY_SCOPE_AGENT);

    { // prefetch next e under the poll (plain cached loads) — r3 placement
      int te2 = dir ? (TS - 2 - t) : (t + 1);
      #pragma unroll
      for (int nt = 0; nt < 4; ++nt)
        #pragma unroll
        for (int i = 0; i < 4; ++i)
          ev[nt][i] = load_e<EF32>(e_in, te2, rb0 + rl + i, d0 + nt * 16 + colq);
    }

    { // poll the 16 same-index wave flags; spin-capped (fail loud, not hung)
      const unsigned tgt = (unsigned)(t + 1);
      unsigned f; int spins = 0;
      do {
        f = __hip_atomic_load(&gflags[(l & 15) * 2 + w],
                              __ATOMIC_RELAXED, __HIP_MEMORY_SCOPE_AGENT);
        if (++spins > (1 << 20)) break;
      } while (!__all((int)(f >= tgt)));
    }
    asm volatile("" ::: "memory");

    // carry' = s @ W : r3-verbatim 8/8 double-buffered s-loads + MFMA chunks
    const unsigned short* srow = sb + (((unsigned)((w << 4) + (l & 15))) << 10) + ((l >> 4) << 3);
    f32x4 c0 = (f32x4){0,0,0,0}, c1 = (f32x4){0,0,0,0};
    f32x4 c2 = (f32x4){0,0,0,0}, c3 = (f32x4){0,0,0,0};
    bf16x8 af[2][8];
    #pragma unroll
    for (int ki = 0; ki < 8; ++ki){
      const unsigned short* p = srow + ki * 32;
      asm volatile("global_load_dwordx4 %0, %1, off sc0 sc1" : "=v"(af[0][ki]) : "v"(p));
    }
    #pragma unroll
    for (int kc = 0; kc < 4; ++kc){
      if (kc < 3){
        #pragma unroll
        for (int ki = 0; ki < 8; ++ki){
          const unsigned short* p = srow + (kc + 1) * 256 + ki * 32;
          asm volatile("global_load_dwordx4 %0, %1, off sc0 sc1" : "=v"(af[(kc + 1) & 1][ki]) : "v"(p));
        }
        asm volatile("s_waitcnt vmcnt(8)" ::: "memory");
      } else {
        asm volatile("s_waitcnt vmcnt(0)" ::: "memory");
      }
      __builtin_amdgcn_sched_barrier(0);
      #pragma unroll
      for (int ki = 0; ki < 8; ++ki){
        int ks = kc * 8 + ki;
        bf16x8 a = af[kc & 1][ki];
        c0 = __builtin_amdgcn_mfma_f32_16x16x32_bf16(a, wp[          ks * 64 + l], c0, 0, 0, 0);
        c1 = __builtin_amdgcn_mfma_f32_16x16x32_bf16(a, wp[2048 +    ks * 64 + l], c1, 0, 0, 0);
        c2 = __builtin_amdgcn_mfma_f32_16x16x32_bf16(a, wp[4096 +    ks * 64 + l], c2, 0, 0, 0);
        c3 = __builtin_amdgcn_mfma_f32_16x16x32_bf16(a, wp[6144 +    ks * 64 + l], c3, 0, 0, 0);
      }
    }
    acc[0] = c0; acc[1] = c1; acc[2] = c2; acc[3] = c3;
  }
}

// ---- final: out[b] = ([sf, sb] @ v) / 32 ----
__global__ __launch_bounds__(256) void finale(const float* __restrict__ sfin,
                                              const float* __restrict__ v,
                                              float* __restrict__ out){
  const int b = blockIdx.x, tid = threadIdx.x;
  float p = 0.f;
  for (int dd = tid; dd < 2 * DD; dd += 256){
    int dir = dd >> 10, d = dd & 1023;
    p += sfin[(((size_t)(dir * NB + b)) << 10) | (unsigned)d] * v[dd];
  }
  #pragma unroll
  for (int off = 32; off > 0; off >>= 1) p += __shfl_down(p, off, 64);
  __shared__ float red[4];
  if ((tid & 63) == 0) red[tid >> 6] = p;
  __syncthreads();
  if (tid == 0) out[b] = (red[0] + red[1] + red[2] + red[3]) * 0.03125f;
}

extern "C" void kernel_launch(void* const* d_in, const int* in_sizes, int n_in,
                              void* d_out, int out_size, void* d_ws, size_t ws_size,
                              hipStream_t stream){
  const float* inp  = (const float*)d_in[0];
  const float* W    = (const float*)d_in[1];
  const float* U    = (const float*)d_in[2];
  const float* bias = (const float*)d_in[3];
  const float* v    = (const float*)d_in[4];
  float* out = (float*)d_out;

  const size_t e_f32_bytes = (size_t)TS * NB * DD * 4;               // 134 MB
  const size_t rest = 2u * 1024 * 1024 + 512u * 1024 + 512u * 1024 + 4096;
  const int ef32 = (ws_size >= e_f32_bytes + rest) ? 1 : 0;

  char* p = (char*)d_ws;
  void* e_buf = (void*)p;              p += ef32 ? e_f32_bytes : e_f32_bytes / 2;
  unsigned short* whi  = (unsigned short*)p; p += 2u * 1024 * 1024;
  unsigned short* sbuf = (unsigned short*)p; p += 512u * 1024;
  float* sfin = (float*)p;             p += 512u * 1024;
  unsigned int* flags = (unsigned int*)p;    // 4 groups x 256B

  hipMemsetAsync(flags, 0, 4096, stream);
  hipLaunchKernelGGL(wprep, dim3(4096), dim3(256), 0, stream, W, whi);
  if (ef32) hipLaunchKernelGGL((embed_k<1>), dim3(8192), dim3(256), 0, stream, inp, U, bias, e_buf);
  else      hipLaunchKernelGGL((embed_k<0>), dim3(8192), dim3(256), 0, stream, inp, U, bias, e_buf);
  if (ef32) hipLaunchKernelGGL((recur<1>), dim3(64), dim3(128), 0, stream,
                               (const void*)e_buf, whi, sbuf, sfin, flags);
  else      hipLaunchKernelGGL((recur<0>), dim3(64), dim3(128), 0, stream,
                               (const void*)e_buf, whi, sbuf, sfin, flags);
  hipLaunchKernelGGL(finale, dim3(64), dim3(256), 0, stream, sfin, v, out);
}